// Round 4
// baseline (193.076 us; speedup 1.0000x reference)
//
#include <hip/hip_runtime.h>
#include <hip/hip_bf16.h>

#define BB 32
#define NN 4096
#define DDIM 64
#define NCH 8

typedef __attribute__((ext_vector_type(8)))  short bf16x8;
typedef __attribute__((ext_vector_type(16))) float f32x16;
typedef __attribute__((ext_vector_type(4)))  float f32x4;

static __device__ inline unsigned short f2bf(float x) {
  union { float f; unsigned u; } v; v.f = x;
  unsigned r = (v.u + 0x7FFFu + ((v.u >> 16) & 1u)) >> 16;   // RNE
  return (unsigned short)r;
}

// packed fp32x2 -> bf16x2 (RNE, v_cvt_pk_bf16_f32 on gfx950)
static __device__ inline unsigned pk(float a, float b) {
  union { __hip_bfloat162 h; unsigned u; } c;
  c.h = __float22bfloat162_rn(float2{a, b});
  return c.u;
}

// ---------------------------------------------------------------------------
// prep_frag: one streaming pass converting E,F,K,V (fp32) into bf16 MFMA
// fragment layout so proj needs NO gather / NO cvt / NO LDS in its hot loop.
//   Ebt/Fbt: [nbg=n/8][col 0..255][j=n%8]   (2 MB each)
//   Kbt/Vbt: [b][nbg=n/8][d 0..63][j=n%8]   (16 MB each)
// Reads: per j, lanes are consecutive in col/d -> 256B coalesced.
// Writes: bf16x8 per thread, consecutive threads contiguous -> 1KB/wave.
// ---------------------------------------------------------------------------
__global__ __launch_bounds__(256) void prep_frag(
    const float* __restrict__ Eg, const float* __restrict__ Fg,
    const float* __restrict__ Kg, const float* __restrict__ Vg,
    unsigned short* __restrict__ Ebt, unsigned short* __restrict__ Fbt,
    unsigned short* __restrict__ Kbt, unsigned short* __restrict__ Vbt)
{
  const int blk = blockIdx.x, t = threadIdx.x;
  float v[8];
  if (blk < 1024) {
    const int which = blk >> 9;           // 0=E, 1=F
    const int nbg = blk & 511;            // n-octet group: n = nbg*8 + j
    const float* src = (which ? Fg : Eg) + (long)(nbg * 8) * 256 + t;
    unsigned short* dst = (which ? Fbt : Ebt) + ((long)nbg * 256 + t) * 8;
#pragma unroll
    for (int j = 0; j < 8; ++j) v[j] = src[j * 256];
    union { unsigned u[4]; bf16x8 x; } r;
    r.u[0] = pk(v[0], v[1]); r.u[1] = pk(v[2], v[3]);
    r.u[2] = pk(v[4], v[5]); r.u[3] = pk(v[6], v[7]);
    *(bf16x8*)dst = r.x;
  } else {
    const int kb = blk - 1024;
    const int which = kb >> 12;           // 0=K, 1=V  (4096 blocks each)
    const int kb2 = kb & 4095;
    const int b = kb2 >> 7, nb = kb2 & 127;
    const int g = t >> 6, d = t & 63;
    const int nbg = nb * 4 + g;           // n = nbg*8 + j
    const float* src = (which ? Vg : Kg) + ((long)b * NN + nbg * 8) * 64 + d;
    unsigned short* dst = (which ? Vbt : Kbt)
                        + (long)b * 262144 + ((long)nbg * 64 + d) * 8;
#pragma unroll
    for (int j = 0; j < 8; ++j) v[j] = src[j * 64];
    union { unsigned u[4]; bf16x8 x; } r;
    r.u[0] = pk(v[0], v[1]); r.u[1] = pk(v[2], v[3]);
    r.u[2] = pk(v[4], v[5]); r.u[3] = pk(v[6], v[7]);
    *(bf16x8*)dst = r.x;
  }
}

// ---------------------------------------------------------------------------
// proj_gemm v5: direct-fragment GEMM. No LDS, no barriers, no packing.
// Per 32-n step: 8 coalesced 16B bf16x8 loads (L3-warm from prep) + 8 MFMA.
//   mat=0: Kp[k][d] = sum_n E[n][k] K[b][n][d]   (A=BIG(Ebt), B=SML(Kbt))
//   mat=1: Vp[d][k] = sum_n V[b][n][d] F[n][k]   (A=SML(Vbt), B=BIG(Fbt))
// NCH=8 split-K chunks, fp32 partials (unchanged precision).
// ---------------------------------------------------------------------------
template <int MAT>
static __device__ inline void proj_core5(
    const unsigned short* __restrict__ Bigt,   // frag layout, 256 cols
    const unsigned short* __restrict__ Smlt,   // frag layout, 64 cols (this b)
    float* __restrict__ Cg, int w, int h, int lr, int chunk)
{
  f32x16 acc[2][2];
#pragma unroll
  for (int i = 0; i < 2; ++i)
#pragma unroll
    for (int j = 0; j < 2; ++j)
#pragma unroll
      for (int q = 0; q < 16; ++q) acc[i][j][q] = 0.f;

  const int colB = w * 64 + lr;
  // octets g = h and g = 2+h; step nb = chunk*16 + tt
  const unsigned short* pB0 = Bigt + (((long)chunk * 16 * 4 + h) * 256 + colB) * 8;
  const unsigned short* pB1 = pB0 + 2 * 256 * 8;
  const unsigned short* pS0 = Smlt + (((long)chunk * 16 * 4 + h) * 64 + lr) * 8;
  const unsigned short* pS1 = pS0 + 2 * 64 * 8;

#pragma unroll 4
  for (int tt = 0; tt < 16; ++tt) {
    const long ob = (long)tt * (1024 * 8);   // 4 octets * 256 cols * 8
    const long os = (long)tt * (256 * 8);    // 4 octets * 64 cols * 8
    bf16x8 B0a = *(const bf16x8*)(pB0 + ob);
    bf16x8 B0b = *(const bf16x8*)(pB0 + ob + 32 * 8);
    bf16x8 B1a = *(const bf16x8*)(pB1 + ob);
    bf16x8 B1b = *(const bf16x8*)(pB1 + ob + 32 * 8);
    bf16x8 S0a = *(const bf16x8*)(pS0 + os);
    bf16x8 S0b = *(const bf16x8*)(pS0 + os + 32 * 8);
    bf16x8 S1a = *(const bf16x8*)(pS1 + os);
    bf16x8 S1b = *(const bf16x8*)(pS1 + os + 32 * 8);
    if (MAT == 0) {   // A=BIG (m=k wave-split), B=SML (n=d)
      acc[0][0] = __builtin_amdgcn_mfma_f32_32x32x16_bf16(B0a, S0a, acc[0][0], 0, 0, 0);
      acc[0][1] = __builtin_amdgcn_mfma_f32_32x32x16_bf16(B0a, S0b, acc[0][1], 0, 0, 0);
      acc[1][0] = __builtin_amdgcn_mfma_f32_32x32x16_bf16(B0b, S0a, acc[1][0], 0, 0, 0);
      acc[1][1] = __builtin_amdgcn_mfma_f32_32x32x16_bf16(B0b, S0b, acc[1][1], 0, 0, 0);
      acc[0][0] = __builtin_amdgcn_mfma_f32_32x32x16_bf16(B1a, S1a, acc[0][0], 0, 0, 0);
      acc[0][1] = __builtin_amdgcn_mfma_f32_32x32x16_bf16(B1a, S1b, acc[0][1], 0, 0, 0);
      acc[1][0] = __builtin_amdgcn_mfma_f32_32x32x16_bf16(B1b, S1a, acc[1][0], 0, 0, 0);
      acc[1][1] = __builtin_amdgcn_mfma_f32_32x32x16_bf16(B1b, S1b, acc[1][1], 0, 0, 0);
    } else {          // A=SML (m=d), B=BIG (n=k wave-split)
      acc[0][0] = __builtin_amdgcn_mfma_f32_32x32x16_bf16(S0a, B0a, acc[0][0], 0, 0, 0);
      acc[0][1] = __builtin_amdgcn_mfma_f32_32x32x16_bf16(S0a, B0b, acc[0][1], 0, 0, 0);
      acc[1][0] = __builtin_amdgcn_mfma_f32_32x32x16_bf16(S0b, B0a, acc[1][0], 0, 0, 0);
      acc[1][1] = __builtin_amdgcn_mfma_f32_32x32x16_bf16(S0b, B0b, acc[1][1], 0, 0, 0);
      acc[0][0] = __builtin_amdgcn_mfma_f32_32x32x16_bf16(S1a, B1a, acc[0][0], 0, 0, 0);
      acc[0][1] = __builtin_amdgcn_mfma_f32_32x32x16_bf16(S1a, B1b, acc[0][1], 0, 0, 0);
      acc[1][0] = __builtin_amdgcn_mfma_f32_32x32x16_bf16(S1b, B1a, acc[1][0], 0, 0, 0);
      acc[1][1] = __builtin_amdgcn_mfma_f32_32x32x16_bf16(S1b, B1b, acc[1][1], 0, 0, 0);
    }
  }

  const int mAdd = (MAT == 0) ? w * 64 : 0;
  const int nAdd = (MAT == 0) ? 0 : w * 64;
  const int OS   = (MAT == 0) ? 64 : 256;
#pragma unroll
  for (int mt = 0; mt < 2; ++mt)
#pragma unroll
    for (int nt = 0; nt < 2; ++nt)
#pragma unroll
      for (int i = 0; i < 16; ++i) {
        int ro  = (i & 3) + 8 * (i >> 2) + 4 * h;       // C/D row map
        int row = mAdd + mt * 32 + ro;
        int col = nAdd + nt * 32 + lr;
        Cg[row * OS + col] = acc[mt][nt][i];
      }
}

__global__ __launch_bounds__(256, 2) void proj_gemm(
    const unsigned short* __restrict__ Ebt, const unsigned short* __restrict__ Fbt,
    const unsigned short* __restrict__ Kbt, const unsigned short* __restrict__ Vbt,
    float* __restrict__ KpP, float* __restrict__ VpP)
{
  const int blk = blockIdx.x;
  const int chunk = blk % NCH;                    // chunk ~ XCD id -> BIG chunk L2-pinned
  const int mat = (blk / NCH) & 1, b = blk / (2 * NCH);
  const int t = threadIdx.x, w = t >> 6, l = t & 63, h = l >> 5, lr = l & 31;
  const long PSTR = (long)BB * 16384;

  if (mat == 0) {
    proj_core5<0>(Ebt, Kbt + (long)b * 262144,
                  KpP + (long)chunk * PSTR + b * 16384, w, h, lr, chunk);
  } else {
    proj_core5<1>(Fbt, Vbt + (long)b * 262144,
                  VpP + (long)chunk * PSTR + b * 16384, w, h, lr, chunk);
  }
}

// ---------------------------------------------------------------------------
// reduce_cvt: sum NCH fp32 partials -> bf16. blocks [0,256): Kp, [256,512): Vp.
// ---------------------------------------------------------------------------
__global__ __launch_bounds__(256) void reduce_cvt(
    const float* __restrict__ KpP, const float* __restrict__ VpP,
    unsigned short* __restrict__ Kpb, unsigned short* __restrict__ Vpb)
{
  const int blk = blockIdx.x;
  const float* src = (blk < 256) ? KpP : VpP;
  unsigned short* dst = (blk < 256) ? Kpb : Vpb;
  const long i = (long)(blk & 255) * 2048 + threadIdx.x * 8;
  float a[8];
#pragma unroll
  for (int j = 0; j < 8; ++j) a[j] = 0.f;
#pragma unroll
  for (int cch = 0; cch < NCH; ++cch) {
    const float4 p0 = *(const float4*)(src + (long)cch * (BB * 16384) + i);
    const float4 p1 = *(const float4*)(src + (long)cch * (BB * 16384) + i + 4);
    a[0] += p0.x; a[1] += p0.y; a[2] += p0.z; a[3] += p0.w;
    a[4] += p1.x; a[5] += p1.y; a[6] += p1.z; a[7] += p1.w;
  }
  unsigned short o[8];
#pragma unroll
  for (int j = 0; j < 8; ++j) o[j] = f2bf(a[j]);
  *(bf16x8*)(dst + i) = *(const bf16x8*)&o[0];
}

// ---------------------------------------------------------------------------
// attn2 v2: Kp/Vp staged ONCE into XOR-swizzled LDS (reg-staged writes, so
// swizzle is legal); kt-loop frag reads become ds_read_b128 — removes the
// per-kt global loads the compiler was serializing under VGPR pressure.
// swzK: byte ^ ((row&7)<<4) with 128B rows; swzV same with 512B rows.
// LDS reused as O_lds for the output transpose (barrier-guarded).
// ---------------------------------------------------------------------------
__global__ __launch_bounds__(256, 2) void attn2_kernel(
    const float* __restrict__ Qg, const unsigned short* __restrict__ Kpb,
    const unsigned short* __restrict__ Vpb, float* __restrict__ Og)
{
  extern __shared__ char smem[];            // 64 KB: [Ksh 32K | Vsh 32K] -> O_lds

  const int blk = blockIdx.x;
  const int b = blk >> 4, rg = blk & 15;
  const int t = threadIdx.x, w = t >> 6, l = t & 63;
  const int h = l >> 5, lr = l & 31;
  const int rbase = rg * 256 + w * 64;

  // ---- Q B-frags for 2 row-tiles (HBM; issue first)
  bf16x8 Bq[2][4];
#pragma unroll
  for (int rt = 0; rt < 2; ++rt)
#pragma unroll
    for (int kk = 0; kk < 4; ++kk) {
      const float* qp = Qg + ((long)b * NN + rbase + rt * 32 + lr) * 64 + kk * 16 + h * 8;
      float4 x = *(const float4*)qp;
      float4 y = *(const float4*)(qp + 4);
      union { unsigned u[4]; bf16x8 v; } r;
      r.u[0] = pk(x.x, x.y); r.u[1] = pk(x.z, x.w);
      r.u[2] = pk(y.x, y.y); r.u[3] = pk(y.z, y.w);
      Bq[rt][kk] = r.v;
    }

  // ---- stage Kp [256 rows x 128B] and Vp [64 rows x 512B] with XOR swizzle
  {
    const uint4* gk = (const uint4*)(Kpb + (long)b * 16384);
    const uint4* gv = (const uint4*)(Vpb + (long)b * 16384);
#pragma unroll
    for (int i = 0; i < 8; ++i) {
      int u = i * 256 + t;                               // 16B unit
      uint4 x = gk[u];
      int kbyte = (u * 16) ^ (((u >> 3) & 7) << 4);      // row = u>>3
      *(uint4*)(smem + kbyte) = x;
      uint4 y = gv[u];
      int vbyte = (u * 16) ^ (((u >> 5) & 7) << 4);      // row = u>>5
      *(uint4*)(smem + 32768 + vbyte) = y;
    }
  }
  __syncthreads();

  f32x16 o[2][2];                           // [row-tile][d-tile]
#pragma unroll
  for (int rt = 0; rt < 2; ++rt)
#pragma unroll
    for (int dt = 0; dt < 2; ++dt)
#pragma unroll
      for (int q = 0; q < 16; ++q) o[rt][dt][q] = 0.f;
  float rowpart[2] = {0.f, 0.f};

  union UV { uint4 u; bf16x8 v; };
  const int swz = (lr & 7) << 4;            // row&7 == lr&7 for all rows used

#pragma unroll
  for (int kt = 0; kt < 8; ++kt) {
    // Kp A-frags: row = kt*32+lr (128B rows)
    bf16x8 Ak[4];
#pragma unroll
    for (int kk = 0; kk < 4; ++kk) {
      int byte = (kt * 32 + lr) * 128 + kk * 32 + h * 16;
      Ak[kk] = *(const bf16x8*)(smem + (byte ^ swz));
    }
    // Vp A-frags: row = dt*32+lr (512B rows)
    bf16x8 Av[2][2];
#pragma unroll
    for (int dt = 0; dt < 2; ++dt)
#pragma unroll
      for (int kc = 0; kc < 2; ++kc) {
        int byte = (dt * 32 + lr) * 512 + (kt * 2 + kc) * 32 + h * 16;
        Av[dt][kc] = *(const bf16x8*)(smem + 32768 + (byte ^ swz));
      }

#pragma unroll
    for (int rt = 0; rt < 2; ++rt) {
      f32x16 s;
#pragma unroll
      for (int q = 0; q < 16; ++q) s[q] = 0.f;
#pragma unroll
      for (int kk = 0; kk < 4; ++kk)
        s = __builtin_amdgcn_mfma_f32_32x32x16_bf16(Ak[kk], Bq[rt][kk], s, 0, 0, 0);

      // exp(s/8) = exp2(s*log2(e)/8); no max-subtract (fp32-safe)
      float p[16];
#pragma unroll
      for (int q = 0; q < 16; ++q) p[q] = exp2f(s[q] * 0.1803368801f);
      rowpart[rt] += (((p[0] + p[1]) + (p[2] + p[3])) + ((p[4] + p[5]) + (p[6] + p[7])))
                   + (((p[8] + p[9]) + (p[10] + p[11])) + ((p[12] + p[13]) + (p[14] + p[15])));

      unsigned wv[8];
#pragma unroll
      for (int m = 0; m < 8; ++m) wv[m] = pk(p[2 * m], p[2 * m + 1]);
      // half-wave exchange: C-layout k=(q&3)+8(q>>2)+4h -> B-layout k=h*8+j
      unsigned r02 = __shfl_xor(h ? wv[0] : wv[2], 32);
      unsigned r13 = __shfl_xor(h ? wv[1] : wv[3], 32);
      unsigned r46 = __shfl_xor(h ? wv[4] : wv[6], 32);
      unsigned r57 = __shfl_xor(h ? wv[5] : wv[7], 32);
      UV c0, c1;
      if (h == 0) {
        c0.u = uint4{wv[0], wv[1], r02, r13};
        c1.u = uint4{wv[4], wv[5], r46, r57};
      } else {
        c0.u = uint4{r02, r13, wv[2], wv[3]};
        c1.u = uint4{r46, r57, wv[6], wv[7]};
      }
      // incremental PV: consume immediately, nothing stays live
      o[rt][0] = __builtin_amdgcn_mfma_f32_32x32x16_bf16(Av[0][0], c0.v, o[rt][0], 0, 0, 0);
      o[rt][0] = __builtin_amdgcn_mfma_f32_32x32x16_bf16(Av[0][1], c1.v, o[rt][0], 0, 0, 0);
      o[rt][1] = __builtin_amdgcn_mfma_f32_32x32x16_bf16(Av[1][0], c0.v, o[rt][1], 0, 0, 0);
      o[rt][1] = __builtin_amdgcn_mfma_f32_32x32x16_bf16(Av[1][1], c1.v, o[rt][1], 0, 0, 0);
    }
  }

  __syncthreads();                          // all Ksh/Vsh reads done; reuse as O_lds
  float* O_lds = (float*)smem;

  // ---- normalize (rowsum at lane=row) and transpose via swizzled LDS
#pragma unroll
  for (int rt = 0; rt < 2; ++rt) {
    float rowsum = rowpart[rt] + __shfl_xor(rowpart[rt], 32);
    float inv = __builtin_amdgcn_rcpf(rowsum);
    const int r = w * 64 + rt * 32 + lr;
#pragma unroll
    for (int dt = 0; dt < 2; ++dt)
#pragma unroll
      for (int qg = 0; qg < 4; ++qg) {
        f32x4 vq;
        vq[0] = o[rt][dt][qg * 4 + 0] * inv;
        vq[1] = o[rt][dt][qg * 4 + 1] * inv;
        vq[2] = o[rt][dt][qg * 4 + 2] * inv;
        vq[3] = o[rt][dt][qg * 4 + 3] * inv;
        int cd = dt * 8 + 2 * qg + h;        // d-chunk (4 dwords)
        int cp = cd ^ (r & 15);              // XOR swizzle
        *(f32x4*)&O_lds[r * 64 + cp * 4] = vq;
      }
  }
  __syncthreads();

  const long obase = ((long)b * NN + rg * 256) * 64;
#pragma unroll
  for (int i = 0; i < 16; ++i) {
    int ci = i * 256 + t;
    int rr = ci >> 4, cc = ci & 15, cp = cc ^ (rr & 15);
    *(float4*)(Og + obase + rr * 64 + cc * 4) = *(const float4*)&O_lds[rr * 64 + cp * 4];
  }
}

extern "C" void kernel_launch(void* const* d_in, const int* in_sizes, int n_in,
                              void* d_out, int out_size, void* d_ws, size_t ws_size,
                              hipStream_t stream) {
  const float* Q = (const float*)d_in[0];
  const float* K = (const float*)d_in[1];
  const float* V = (const float*)d_in[2];
  const float* E = (const float*)d_in[3];
  const float* F = (const float*)d_in[4];
  float* out = (float*)d_out;

  // workspace layout (70 MB total)
  char* ws = (char*)d_ws;
  float*          KpP = (float*)(ws);                          // 16 MB
  float*          VpP = (float*)(ws + (16l << 20));            // 16 MB
  unsigned short* Kpb = (unsigned short*)(ws + (32l << 20));   // 1 MB
  unsigned short* Vpb = (unsigned short*)(ws + (33l << 20));   // 1 MB
  unsigned short* Ebt = (unsigned short*)(ws + (34l << 20));   // 2 MB
  unsigned short* Fbt = (unsigned short*)(ws + (36l << 20));   // 2 MB
  unsigned short* Kbt = (unsigned short*)(ws + (38l << 20));   // 16 MB
  unsigned short* Vbt = (unsigned short*)(ws + (54l << 20));   // 16 MB

  hipFuncSetAttribute((const void*)attn2_kernel,
                      hipFuncAttributeMaxDynamicSharedMemorySize, 65536);

  prep_frag<<<dim3(9216), dim3(256), 0, stream>>>(E, F, K, V, Ebt, Fbt, Kbt, Vbt);

  proj_gemm<<<dim3(512), dim3(256), 0, stream>>>(Ebt, Fbt, Kbt, Vbt, KpP, VpP);

  reduce_cvt<<<dim3(512), dim3(256), 0, stream>>>(KpP, VpP, Kpb, Vpb);

  attn2_kernel<<<dim3(512), dim3(256), 65536, stream>>>(Q, Kpb, Vpb, out);
}